// Round 7
// baseline (112.960 us; speedup 1.0000x reference)
//
#include <hip/hip_runtime.h>
#include <math.h>

#define BB 256
#define VV 400000
#define NR 500
#define D1 128
#define D2 128
#define PP 64
#define KK 30
#define TT 20
#define XSTRIDE 32   // x rows padded to 32 bf16 (64 B)
#define BN_EPS 1e-5f
// 1/sqrt(K*T) = 1/sqrt(600)
#define FACTOR 0.04082482904638631f

#define VB 320       // v-columns per block in stage2 (400000/320 = 1250 blocks)
#define NSUB 5       // 16-v subtiles per wave (VB / (4 waves * 16))
#define LSTR 324     // LDS tile row stride in dwords (320 + 4 pad -> 2-way banks)

typedef __attribute__((ext_vector_type(8))) short bf16x8;
typedef __attribute__((ext_vector_type(4))) float f32x4;

static __device__ inline unsigned short f2bf(float f) {
    union { float f; unsigned u; } x; x.f = f;
    unsigned r = x.u + 0x7fff + ((x.u >> 16) & 1);   // RNE
    return (unsigned short)(r >> 16);
}

// ---------------- Kernel 1: compute x[B][K] -> bf16, pad to 32 -------------
// One block (1 wave, 64 threads) per batch row.
__global__ __launch_bounds__(64) void lowfer_stage1(
    const int* __restrict__ e1_idx, const int* __restrict__ r_idx,
    const float* __restrict__ E, const float* __restrict__ R,
    const float* __restrict__ proj, const int* __restrict__ idx,
    const float* __restrict__ g0, const float* __restrict__ b0,
    const float* __restrict__ m0, const float* __restrict__ v0,
    const float* __restrict__ g1, const float* __restrict__ b1,
    const float* __restrict__ m1, const float* __restrict__ v1,
    unsigned short* __restrict__ xwb)
{
    __shared__ float e1s[D1];
    __shared__ float rs[D1];
    __shared__ float ses[PP];
    __shared__ float srs[PP];
    __shared__ float xsq[KK];

    const int tid = threadIdx.x;
    const int row = blockIdx.x;

    const int eix = e1_idx[row];
    const int rix = r_idx[row];

    for (int j = tid; j < D1; j += 64) {
        float ev = E[(size_t)eix * D1 + j];
        e1s[j] = (ev - m0[j]) * rsqrtf(v0[j] + BN_EPS) * g0[j] + b0[j];
        rs[j]  = R[(size_t)rix * D2 + j];
    }
    __syncthreads();

    float se = 0.f, sr = 0.f;
#pragma unroll 4
    for (int d = 0; d < D1; ++d) {
        float pv = proj[d * PP + tid];
        se += e1s[d] * pv;
        sr += rs[d]  * pv;
    }
    ses[tid] = se;
    srs[tid] = sr;
    __syncthreads();

    float xv = 0.f;
    if (tid < KK) {
        float y = 0.f;
        for (int t = 0; t < TT; ++t) {
            int i0 = idx[(tid * TT + t) * 2 + 0];
            int i1 = idx[(tid * TT + t) * 2 + 1];
            y += ses[i0] * srs[i1];
        }
        y *= FACTOR;
        float s = (y > 0.f) ? 1.f : ((y < 0.f) ? -1.f : 0.f);
        xv = s * sqrtf(fabsf(y) + 1e-12f);
        xsq[tid] = xv * xv;
    }
    __syncthreads();

    if (tid < XSTRIDE) {
        float val = 0.f;
        if (tid < KK) {
            float ss = 0.f;
#pragma unroll
            for (int k = 0; k < KK; ++k) ss += xsq[k];
            float nrm = fmaxf(sqrtf(ss), 1e-12f);
            float xn = xv / nrm;
            val = (xn - m1[tid]) * rsqrtf(v1[tid] + BN_EPS) * g1[tid] + b1[tid];
        }
        xwb[row * XSTRIDE + tid] = f2bf(val);
    }
}

// ---------------- Kernel 2: out = sigmoid(x @ E30^T) via MFMA --------------
// Block = 256 thr (4 waves) covering VB=320 v-cols x all 256 b-rows.
// Each wave owns 80 v (5 16x16 subtiles). Per b-tile: 5 MFMA, sigmoid in
// registers, transpose via LDS, then a flat f32x4 store phase. Stores are
// PLAIN (not nontemporal) this round: single-variable A/B vs round 6 —
// let L2/MALL absorb and schedule the writeback stream like fillBuffer does.
__global__ __launch_bounds__(256) void lowfer_stage2(
    const float* __restrict__ E, const unsigned short* __restrict__ xwb,
    float* __restrict__ out)
{
    __shared__ float tile[16 * LSTR];   // 16*324*4 B = 20.7 KB

    const int tid  = threadIdx.x;
    const int wid  = tid >> 6;
    const int lane = tid & 63;
    const int col  = lane & 15;     // v within subtile / C col
    const int kq   = lane >> 4;     // k quarter (8 k each)
    const int vbase = blockIdx.x * VB;

    // B fragments: E[v][kq*8 ..] -> bf16 for NSUB subtiles; zero k>=30.
    bf16x8 bfr[NSUB];
#pragma unroll
    for (int t = 0; t < NSUB; ++t) {
        const int v = vbase + wid * (NSUB * 16) + t * 16 + col;
        const float* Ep = E + (size_t)v * D1 + kq * 8;
        float4 a0 = *(const float4*)(Ep);
        float4 a1 = *(const float4*)(Ep + 4);
        if (kq == 3) { a1.z = 0.f; a1.w = 0.f; }
        bfr[t][0] = (short)f2bf(a0.x); bfr[t][1] = (short)f2bf(a0.y);
        bfr[t][2] = (short)f2bf(a0.z); bfr[t][3] = (short)f2bf(a0.w);
        bfr[t][4] = (short)f2bf(a1.x); bfr[t][5] = (short)f2bf(a1.y);
        bfr[t][6] = (short)f2bf(a1.z); bfr[t][7] = (short)f2bf(a1.w);
    }

    const f32x4 zero = {0.f, 0.f, 0.f, 0.f};

    for (int bt = 0; bt < 16; ++bt) {
        // A fragment: x[bt*16 + col][kq*8 ..] (bf16, 64 B rows, 16 B aligned)
        bf16x8 af = *(const bf16x8*)(xwb + (bt * 16 + col) * XSTRIDE + kq * 8);

        // 5 MFMA + sigmoid in registers (no LDS yet).
        float sg[NSUB][4];
#pragma unroll
        for (int t = 0; t < NSUB; ++t) {
            f32x4 acc = __builtin_amdgcn_mfma_f32_16x16x32_bf16(af, bfr[t], zero, 0, 0, 0);
#pragma unroll
            for (int i = 0; i < 4; ++i)
                sg[t][i] = __builtin_amdgcn_rcpf(1.f + __expf(-acc[i]));
        }

        __syncthreads();   // WAR: previous iteration's store-phase readers done

        // C/D layout: col = lane&15 (v), row = kq*4 + i (b within tile).
        // LDS banks: (row*LSTR + c)%32 = (4*row + c)%32 -> 2-way (free).
#pragma unroll
        for (int t = 0; t < NSUB; ++t) {
            const int c = wid * (NSUB * 16) + t * 16 + col;
#pragma unroll
            for (int i = 0; i < 4; ++i)
                tile[(kq * 4 + i) * LSTR + c] = sg[t][i];
        }
        __syncthreads();

        // Flat store phase: 16 rows x 320 floats = 1280 f32x4 slots over
        // 256 threads = 5 slots each. 1024 B contiguous per wave-instr.
#pragma unroll
        for (int j = 0; j < 5; ++j) {
            const int s   = j * 256 + tid;
            const int row = s / 80;        // 80 f32x4 slots per row
            const int c4  = s % 80;
            f32x4 d = *(const f32x4*)&tile[row * LSTR + c4 * 4];
            *(f32x4*)&out[(size_t)(bt * 16 + row) * VV + vbase + c4 * 4] = d;
        }
    }
}

extern "C" void kernel_launch(void* const* d_in, const int* in_sizes, int n_in,
                              void* d_out, int out_size, void* d_ws, size_t ws_size,
                              hipStream_t stream) {
    const int*   e1_idx = (const int*)  d_in[0];
    const int*   r_idx  = (const int*)  d_in[1];
    const float* E      = (const float*)d_in[2];
    const float* R      = (const float*)d_in[3];
    const float* proj   = (const float*)d_in[4];
    const int*   idx    = (const int*)  d_in[5];
    const float* g0     = (const float*)d_in[6];
    const float* b0     = (const float*)d_in[7];
    const float* m0     = (const float*)d_in[8];
    const float* v0     = (const float*)d_in[9];
    const float* g1     = (const float*)d_in[10];
    const float* b1     = (const float*)d_in[11];
    const float* m1     = (const float*)d_in[12];
    const float* v1     = (const float*)d_in[13];
    float* out = (float*)d_out;
    unsigned short* xwb = (unsigned short*)d_ws;   // 256*32 bf16 = 16 KB

    lowfer_stage1<<<BB, 64, 0, stream>>>(e1_idx, r_idx, E, R, proj, idx,
                                         g0, b0, m0, v0, g1, b1, m1, v1, xwb);

    lowfer_stage2<<<VV / VB, 256, 0, stream>>>(E, xwb, out);
}

// Round 8
// 99.716 us; speedup vs baseline: 1.1328x; 1.1328x over previous
//
#include <hip/hip_runtime.h>
#include <math.h>

#define BB 256
#define VV 400000
#define NR 500
#define D1 128
#define D2 128
#define PP 64
#define KK 30
#define TT 20
#define XSTRIDE 32   // x rows padded to 32 bf16 (64 B)
#define BN_EPS 1e-5f
// 1/sqrt(K*T) = 1/sqrt(600)
#define FACTOR 0.04082482904638631f

#define VB 320       // v-columns per block in stage2 (400000/320 = 1250 blocks)
#define NSUB 5       // 16-v subtiles per wave (VB / (4 waves * 16))
#define LSTR 324     // LDS tile row stride in dwords (320 + 4 pad -> 2-way banks)

typedef __attribute__((ext_vector_type(8))) short bf16x8;
typedef __attribute__((ext_vector_type(4))) float f32x4;

static __device__ inline unsigned short f2bf(float f) {
    union { float f; unsigned u; } x; x.f = f;
    unsigned r = x.u + 0x7fff + ((x.u >> 16) & 1);   // RNE
    return (unsigned short)(r >> 16);
}

// ---------------- Kernel 1: compute x[B][K] -> bf16, pad to 32 -------------
// One block (1 wave, 64 threads) per batch row.
__global__ __launch_bounds__(64) void lowfer_stage1(
    const int* __restrict__ e1_idx, const int* __restrict__ r_idx,
    const float* __restrict__ E, const float* __restrict__ R,
    const float* __restrict__ proj, const int* __restrict__ idx,
    const float* __restrict__ g0, const float* __restrict__ b0,
    const float* __restrict__ m0, const float* __restrict__ v0,
    const float* __restrict__ g1, const float* __restrict__ b1,
    const float* __restrict__ m1, const float* __restrict__ v1,
    unsigned short* __restrict__ xwb)
{
    __shared__ float e1s[D1];
    __shared__ float rs[D1];
    __shared__ float ses[PP];
    __shared__ float srs[PP];
    __shared__ float xsq[KK];

    const int tid = threadIdx.x;
    const int row = blockIdx.x;

    const int eix = e1_idx[row];
    const int rix = r_idx[row];

    for (int j = tid; j < D1; j += 64) {
        float ev = E[(size_t)eix * D1 + j];
        e1s[j] = (ev - m0[j]) * rsqrtf(v0[j] + BN_EPS) * g0[j] + b0[j];
        rs[j]  = R[(size_t)rix * D2 + j];
    }
    __syncthreads();

    float se = 0.f, sr = 0.f;
#pragma unroll 4
    for (int d = 0; d < D1; ++d) {
        float pv = proj[d * PP + tid];
        se += e1s[d] * pv;
        sr += rs[d]  * pv;
    }
    ses[tid] = se;
    srs[tid] = sr;
    __syncthreads();

    float xv = 0.f;
    if (tid < KK) {
        float y = 0.f;
        for (int t = 0; t < TT; ++t) {
            int i0 = idx[(tid * TT + t) * 2 + 0];
            int i1 = idx[(tid * TT + t) * 2 + 1];
            y += ses[i0] * srs[i1];
        }
        y *= FACTOR;
        float s = (y > 0.f) ? 1.f : ((y < 0.f) ? -1.f : 0.f);
        xv = s * sqrtf(fabsf(y) + 1e-12f);
        xsq[tid] = xv * xv;
    }
    __syncthreads();

    if (tid < XSTRIDE) {
        float val = 0.f;
        if (tid < KK) {
            float ss = 0.f;
#pragma unroll
            for (int k = 0; k < KK; ++k) ss += xsq[k];
            float nrm = fmaxf(sqrtf(ss), 1e-12f);
            float xn = xv / nrm;
            val = (xn - m1[tid]) * rsqrtf(v1[tid] + BN_EPS) * g1[tid] + b1[tid];
        }
        xwb[row * XSTRIDE + tid] = f2bf(val);
    }
}

// ---------------- Kernel 2: out = sigmoid(x @ E30^T) via MFMA --------------
// Block = 256 thr (4 waves) covering VB=320 v-cols x all 256 b-rows.
// Store-pipelining version: ALL A-fragments prefetched into VGPRs before the
// loop (no vmem reads inside), raw s_barrier + lgkmcnt-only drains (no
// implicit vmcnt(0) from __syncthreads) -> nt-stores stay in flight across
// all 16 iterations instead of draining at every barrier.
__global__ __launch_bounds__(256) void lowfer_stage2(
    const float* __restrict__ E, const unsigned short* __restrict__ xwb,
    float* __restrict__ out)
{
    __shared__ float tile[2][16 * LSTR];   // double buffer, 2*20.7 KB

    const int tid  = threadIdx.x;
    const int wid  = tid >> 6;
    const int lane = tid & 63;
    const int col  = lane & 15;     // v within subtile / C col
    const int kq   = lane >> 4;     // k quarter (8 k each)
    const int vbase = blockIdx.x * VB;

    // B fragments: E[v][kq*8 ..] -> bf16 for NSUB subtiles; zero k>=30.
    bf16x8 bfr[NSUB];
#pragma unroll
    for (int t = 0; t < NSUB; ++t) {
        const int v = vbase + wid * (NSUB * 16) + t * 16 + col;
        const float* Ep = E + (size_t)v * D1 + kq * 8;
        float4 a0 = *(const float4*)(Ep);
        float4 a1 = *(const float4*)(Ep + 4);
        if (kq == 3) { a1.z = 0.f; a1.w = 0.f; }
        bfr[t][0] = (short)f2bf(a0.x); bfr[t][1] = (short)f2bf(a0.y);
        bfr[t][2] = (short)f2bf(a0.z); bfr[t][3] = (short)f2bf(a0.w);
        bfr[t][4] = (short)f2bf(a1.x); bfr[t][5] = (short)f2bf(a1.y);
        bfr[t][6] = (short)f2bf(a1.z); bfr[t][7] = (short)f2bf(a1.w);
    }

    // Prefetch ALL 16 A-fragments (x for every b-tile) into registers.
    // 16 x dwordx4 = 64 VGPR; xwb is 16 KB and L2-hot. After this, the main
    // loop issues ZERO vmem reads -> no vmcnt waits -> stores never drain.
    bf16x8 afr[16];
#pragma unroll
    for (int bt = 0; bt < 16; ++bt)
        afr[bt] = *(const bf16x8*)(xwb + (bt * 16 + col) * XSTRIDE + kq * 8);

    const f32x4 zero = {0.f, 0.f, 0.f, 0.f};

#pragma unroll
    for (int bt = 0; bt < 16; ++bt) {
        float* tb = tile[bt & 1];   // static after full unroll (rule #20)

        // 5 MFMA + sigmoid in registers.
        float sg[NSUB][4];
#pragma unroll
        for (int t = 0; t < NSUB; ++t) {
            f32x4 acc = __builtin_amdgcn_mfma_f32_16x16x32_bf16(afr[bt], bfr[t], zero, 0, 0, 0);
#pragma unroll
            for (int i = 0; i < 4; ++i)
                sg[t][i] = __builtin_amdgcn_rcpf(1.f + __expf(-acc[i]));
        }

        // Transpose to LDS. C/D layout: col=lane&15 (v), row=kq*4+i (b).
        // Banks: (row*LSTR + c) % 32 -> 2-way (free, m136).
#pragma unroll
        for (int t = 0; t < NSUB; ++t) {
            const int c = wid * (NSUB * 16) + t * 16 + col;
#pragma unroll
            for (int i = 0; i < 4; ++i)
                tb[(kq * 4 + i) * LSTR + c] = sg[t][i];
        }

        // LDS-only drain + raw barrier: ds_writes visible to all waves, and
        // (at iter i+1) guarantees iter i's ds_reads completed -> WAR on
        // tile[(i+2)&1] is safe. NO vmcnt: nt-stores stay in flight.
        asm volatile("s_waitcnt lgkmcnt(0)" ::: "memory");
        __builtin_amdgcn_s_barrier();
        __builtin_amdgcn_sched_barrier(0);

        // Flat store phase: 16 rows x 320 floats = 1280 f32x4 slots over
        // 256 threads = 5 slots each. 1024 B contiguous per wave-instr.
#pragma unroll
        for (int j = 0; j < 5; ++j) {
            const int s   = j * 256 + tid;
            const int row = s / 80;        // 80 f32x4 slots per row
            const int c4  = s % 80;
            f32x4 d = *(const f32x4*)&tb[row * LSTR + c4 * 4];
            __builtin_nontemporal_store(
                d, (f32x4*)&out[(size_t)(bt * 16 + row) * VV + vbase + c4 * 4]);
        }
    }
}

extern "C" void kernel_launch(void* const* d_in, const int* in_sizes, int n_in,
                              void* d_out, int out_size, void* d_ws, size_t ws_size,
                              hipStream_t stream) {
    const int*   e1_idx = (const int*)  d_in[0];
    const int*   r_idx  = (const int*)  d_in[1];
    const float* E      = (const float*)d_in[2];
    const float* R      = (const float*)d_in[3];
    const float* proj   = (const float*)d_in[4];
    const int*   idx    = (const int*)  d_in[5];
    const float* g0     = (const float*)d_in[6];
    const float* b0     = (const float*)d_in[7];
    const float* m0     = (const float*)d_in[8];
    const float* v0     = (const float*)d_in[9];
    const float* g1     = (const float*)d_in[10];
    const float* b1     = (const float*)d_in[11];
    const float* m1     = (const float*)d_in[12];
    const float* v1     = (const float*)d_in[13];
    float* out = (float*)d_out;
    unsigned short* xwb = (unsigned short*)d_ws;   // 256*32 bf16 = 16 KB

    lowfer_stage1<<<BB, 64, 0, stream>>>(e1_idx, r_idx, E, R, proj, idx,
                                         g0, b0, m0, v0, g1, b1, m1, v1, xwb);

    lowfer_stage2<<<VV / VB, 256, 0, stream>>>(E, xwb, out);
}